// Round 3
// baseline (418.245 us; speedup 1.0000x reference)
//
#include <hip/hip_runtime.h>

#define H 1024
#define E 64
#define BT 64           // tokens per block
#define BK 64           // k-chunk
#define NCH (H / BK)    // 16 chunks
#define EPW 8           // experts per wave (8 waves x 8 experts = 64)

// Scalar-W scheme, take 3: lane = token, wave w owns experts w*8..w*8+7.
// Round-1 failure: uniform global loads of W stayed VMEM and jammed the
// vector-memory pipe. Fix: W pointer in the CONSTANT address space (AS4):
// clang treats AS4 as invariant, so a wave-uniform AS4 load selects
// s_load_dwordx4 on the scalar K$ pipe -- zero VMEM / LDS / per-lane
// address VALU for W. Round-2 failure was cosmetic: HIP's float4 class
// ctor can't bind across address spaces; use clang's builtin
// ext_vector_type instead (plain load, no ctor).
// Per-CU per-chunk budget @16 waves: VALU 4096 cyc/SIMD (27us fp32 floor),
// LDS 3072 cyc (x only, conflict-free, measured 0 in round 1), SMEM ~3us,
// VMEM ~512 staging loads. VALU-bound.
typedef float __attribute__((ext_vector_type(4))) f4;
typedef const f4 __attribute__((address_space(4)))* cf4p;

__global__ __launch_bounds__(512, 4) void moe_gate_kernel(
    const float* __restrict__ x, const float* __restrict__ W,
    float* __restrict__ out, int T) {
  __shared__ float xs[2][BT][BK + 4];
  // epilogue logits tile overlays xs (dead after K-loop); 64*65*4 = 16640 B
  float(*ls)[E + 1] = (float(*)[E + 1])xs;

  const int tid = threadIdx.x;
  const int lane = tid & 63;                                   // token
  const int wid = __builtin_amdgcn_readfirstlane(tid >> 6);    // wave 0..7
  const int e0 = wid * EPW;
  const int t0 = blockIdx.x * BT;

  // W as f4 array in constant address space; index in f4 granules.
  cf4p Wp = (cf4p)(unsigned long long)W;
  const int wbase = e0 * (H / 4);   // uniform: expert row e0, f4 units

  // staging map: 2 float4 per thread (64 rows x 16 granules = 1024 f4)
  const int r0 = tid >> 4;        // 0..31
  const int c0 = tid & 15;
  const int r1 = r0 + 32;         // 32..63
  const float* xp0 = x + (size_t)(t0 + r0) * H + (c0 << 2);
  const float* xp1 = x + (size_t)(t0 + r1) * H + (c0 << 2);

  float acc[EPW];
#pragma unroll
  for (int e = 0; e < EPW; ++e) acc[e] = 0.f;

  // prologue: stage chunk 0
  {
    f4 a = *(const f4*)xp0;
    f4 b = *(const f4*)xp1;
    *(f4*)&xs[0][r0][c0 << 2] = a;
    *(f4*)&xs[0][r1][c0 << 2] = b;
  }
  __syncthreads();

  for (int c = 0; c < NCH; ++c) {
    const int cur = c & 1;
    const bool more = (c + 1 < NCH);
    // issue next chunk's global loads early (latency hides under FMAs)
    f4 na = {0.f, 0.f, 0.f, 0.f}, nb = {0.f, 0.f, 0.f, 0.f};
    if (more) {
      na = *(const f4*)(xp0 + (c + 1) * BK);
      nb = *(const f4*)(xp1 + (c + 1) * BK);
    }

    // chunk-uniform W base in f4 units: rows e0..e0+7, cols [c*64, c*64+63].
    // All 128 W loads below are constant offsets from this base -> one SGPR
    // base + immediate-offset s_load_dwordx4s, mergeable to x8/x16.
    const int wc = wbase + c * (BK / 4);

#pragma unroll
    for (int j = 0; j < BK / 4; ++j) {
      // this lane's x f4 for k-substep j: ds_read_b128, conflict-free
      f4 xv = *(const f4*)&xs[cur][lane][j << 2];
#pragma unroll
      for (int e = 0; e < EPW; ++e) {
        f4 wv = Wp[wc + e * (H / 4) + j];   // s_load_dwordx4 (uniform)
        acc[e] = fmaf(xv.x, wv.x, acc[e]);
        acc[e] = fmaf(xv.y, wv.y, acc[e]);
        acc[e] = fmaf(xv.z, wv.z, acc[e]);
        acc[e] = fmaf(xv.w, wv.w, acc[e]);
      }
    }

    // write next chunk into the other buffer; one barrier per chunk
    // (buf cur^1 held chunk c-1, all waves finished it before last barrier)
    if (more) {
      *(f4*)&xs[cur ^ 1][r0][c0 << 2] = na;
      *(f4*)&xs[cur ^ 1][r1][c0 << 2] = nb;
    }
    __syncthreads();
  }

  // dump logits tile to LDS for the per-token epilogue (stride 65: conflict-free)
#pragma unroll
  for (int e = 0; e < EPW; ++e) ls[lane][e0 + e] = acc[e];
  __syncthreads();

  // wave 0: one lane per token. top-2 of logits == top-2 of softmax
  // (monotonic); tie-break = lower index first (matches jax.lax.top_k).
  if (tid < BT) {
    const int tk = tid;
    float m1 = -1e30f, m2 = -1e30f;
    int i1 = 0, i2 = 0;
#pragma unroll
    for (int e = 0; e < E; ++e) {
      float v = ls[tk][e];
      if (v > m1) {
        m2 = m1; i2 = i1;
        m1 = v;  i1 = e;
      } else if (v > m2) {
        m2 = v; i2 = e;
      }
    }
    float s = 0.f;
#pragma unroll
    for (int e = 0; e < E; ++e) s += expf(ls[tk][e] - m1);
    float p1 = 1.f / s;                 // exp(m1-m1)/s
    float p2 = expf(m2 - m1) / s;
    // second softmax over [p1, p2] (p1 >= p2 so exponent <= 0: stable)
    float e12 = expf(p2 - p1);
    float s1 = 1.f / (1.f + e12);
    float s2 = e12 * s1;

    size_t t = (size_t)(t0 + tk);
    out[t * 2 + 0] = s1;
    out[t * 2 + 1] = s2;
    float* idxo = out + (size_t)2 * T;
    idxo[t * 2 + 0] = (float)i1;
    idxo[t * 2 + 1] = (float)i2;
  }

  // trailing scalar output: zeros(())
  if (blockIdx.x == 0 && tid == 0) out[(size_t)4 * T] = 0.f;
}

extern "C" void kernel_launch(void* const* d_in, const int* in_sizes, int n_in,
                              void* d_out, int out_size, void* d_ws, size_t ws_size,
                              hipStream_t stream) {
  const float* x = (const float*)d_in[0];
  const float* W = (const float*)d_in[1];
  float* out = (float*)d_out;
  const int T = in_sizes[0] / H;  // 4*8192 = 32768 tokens
  dim3 grid(T / BT), block(512);
  hipLaunchKernelGGL(moe_gate_kernel, grid, block, 0, stream, x, W, out, T);
}